// Round 1
// baseline (868.947 us; speedup 1.0000x reference)
//
#include <hip/hip_runtime.h>

#define D 128

// ---------------- CSR build ----------------

__global__ __launch_bounds__(256) void count_kernel(const int* __restrict__ dst,
                                                    int* __restrict__ cnt, int E) {
    int e = blockIdx.x * 256 + threadIdx.x;
    if (e < E) atomicAdd(&cnt[dst[e]], 1);
}

// Single-block scan: shfl-based wave scans + cross-wave combine.
__global__ __launch_bounds__(1024) void scan_kernel(const int* __restrict__ cnt,
                                                    int* __restrict__ off,
                                                    int* __restrict__ cursor, int n) {
    __shared__ int wsum[16];
    __shared__ int wpre[16];
    __shared__ int carry_s;
    int tid = threadIdx.x;
    if (tid == 0) carry_s = 0;
    __syncthreads();
    int lane = tid & 63, wv = tid >> 6;
    for (int base = 0; base < n; base += 1024) {
        int i = base + tid;
        int v = (i < n) ? cnt[i] : 0;
        int sc = v;
        #pragma unroll
        for (int d = 1; d < 64; d <<= 1) {
            int t = __shfl_up(sc, d, 64);
            if (lane >= d) sc += t;
        }
        if (lane == 63) wsum[wv] = sc;
        __syncthreads();
        if (tid < 16) {
            int ws_ = wsum[tid];
            int sc2 = ws_;
            #pragma unroll
            for (int d = 1; d < 16; d <<= 1) {
                int t = __shfl_up(sc2, d, 64);
                if (tid >= d) sc2 += t;
            }
            wpre[tid] = sc2 - ws_;  // exclusive prefix of wave sums
        }
        __syncthreads();
        int carry = carry_s;
        int incl = carry + wpre[wv] + sc;
        if (i < n) { off[i + 1] = incl; cursor[i] = incl - v; }
        if (i == 0) off[0] = 0;
        __syncthreads();
        if (tid == 0) carry_s = carry + wpre[15] + wsum[15];
        __syncthreads();
    }
}

__global__ __launch_bounds__(256) void fill_kernel(const int* __restrict__ src,
                                                   const int* __restrict__ dst,
                                                   int* __restrict__ cursor,
                                                   int2* __restrict__ pairs, int E) {
    int e = blockIdx.x * 256 + threadIdx.x;
    if (e < E) {
        int d = dst[e];
        int slot = atomicAdd(&cursor[d], 1);
        pairs[slot] = make_int2(src[e], e);
    }
}

// ---------------- mean aggregation of relu(feat[src] + edge_attr) ----------------
// One wave (64 threads) per dst node; float2 per lane covers D=128.

__global__ __launch_bounds__(64) void aggregate_kernel(const float* __restrict__ feat,
                                                       const float* __restrict__ ea,
                                                       const int* __restrict__ off,
                                                       const int2* __restrict__ pairs,
                                                       float* __restrict__ agg) {
    int nd = blockIdx.x;
    int t = threadIdx.x;
    int s = off[nd], e2 = off[nd + 1];
    float accx = 0.f, accy = 0.f;
    for (int p = s; p < e2; ++p) {
        int2 pr = pairs[p];
        const float2 xv = *reinterpret_cast<const float2*>(&feat[(size_t)pr.x * D + 2 * t]);
        const float2 ev = *reinterpret_cast<const float2*>(&ea[(size_t)pr.y * D + 2 * t]);
        accx += fmaxf(xv.x + ev.x, 0.f);
        accy += fmaxf(xv.y + ev.y, 0.f);
    }
    float inv = 1.0f / (float)max(e2 - s, 1);
    float2 r = make_float2(accx * inv, accy * inv);
    *reinterpret_cast<float2*>(&agg[(size_t)nd * D + 2 * t]) = r;
}

// ---------------- fused dual GEMM: out = act(A1@W1 + bias + A2@W2) ----------------
// Block: 256 threads -> 64 nodes x 128 cols. K chunked by 32. LDS = 48 KB.

template <int RELU>
__global__ __launch_bounds__(256) void gemm_fused_kernel(const float* __restrict__ A1,
                                                         const float* __restrict__ A2,
                                                         const float* __restrict__ W1,
                                                         const float* __restrict__ W2,
                                                         const float* __restrict__ bias,
                                                         float* __restrict__ out, int N) {
    __shared__ float sA1[64][32];
    __shared__ float sA2[64][32];
    __shared__ float sW1[32][128];
    __shared__ float sW2[32][128];
    int tid = threadIdx.x;
    int n0 = blockIdx.x * 64;
    int c = tid & 31;   // col group: cols c, c+32, c+64, c+96
    int r = tid >> 5;   // row group: nodes r, r+8, ..., r+56
    float acc[8][4];
    #pragma unroll
    for (int m = 0; m < 8; ++m)
        #pragma unroll
        for (int j = 0; j < 4; ++j) acc[m][j] = 0.f;

    for (int kc = 0; kc < 128; kc += 32) {
        __syncthreads();
        // stage A tiles (64x32 each)
        #pragma unroll
        for (int it = 0; it < 2; ++it) {
            int idx = tid + 256 * it;
            int row = idx >> 3;
            int col = (idx & 7) * 4;
            float4 v1 = make_float4(0.f, 0.f, 0.f, 0.f), v2 = v1;
            if (n0 + row < N) {
                v1 = *reinterpret_cast<const float4*>(&A1[(size_t)(n0 + row) * 128 + kc + col]);
                v2 = *reinterpret_cast<const float4*>(&A2[(size_t)(n0 + row) * 128 + kc + col]);
            }
            *reinterpret_cast<float4*>(&sA1[row][col]) = v1;
            *reinterpret_cast<float4*>(&sA2[row][col]) = v2;
        }
        // stage W tiles (32x128 each)
        #pragma unroll
        for (int it = 0; it < 4; ++it) {
            int idx = tid + 256 * it;
            int row = idx >> 5;
            int col = (idx & 31) * 4;
            *reinterpret_cast<float4*>(&sW1[row][col]) =
                *reinterpret_cast<const float4*>(&W1[(size_t)(kc + row) * 128 + col]);
            *reinterpret_cast<float4*>(&sW2[row][col]) =
                *reinterpret_cast<const float4*>(&W2[(size_t)(kc + row) * 128 + col]);
        }
        __syncthreads();
        #pragma unroll 4
        for (int kk = 0; kk < 32; ++kk) {
            float a1[8], a2[8], w1[4], w2[4];
            #pragma unroll
            for (int m = 0; m < 8; ++m) {
                a1[m] = sA1[r + 8 * m][kk];
                a2[m] = sA2[r + 8 * m][kk];
            }
            #pragma unroll
            for (int j = 0; j < 4; ++j) {
                w1[j] = sW1[kk][c + 32 * j];
                w2[j] = sW2[kk][c + 32 * j];
            }
            #pragma unroll
            for (int m = 0; m < 8; ++m)
                #pragma unroll
                for (int j = 0; j < 4; ++j)
                    acc[m][j] += a1[m] * w1[j] + a2[m] * w2[j];
        }
    }
    float bv[4];
    #pragma unroll
    for (int j = 0; j < 4; ++j) bv[j] = bias[c + 32 * j];
    #pragma unroll
    for (int m = 0; m < 8; ++m) {
        int n = n0 + r + 8 * m;
        if (n < N) {
            #pragma unroll
            for (int j = 0; j < 4; ++j) {
                float v = acc[m][j] + bv[j];
                if (RELU) v = fmaxf(v, 0.f);
                out[(size_t)n * 128 + c + 32 * j] = v;
            }
        }
    }
}

extern "C" void kernel_launch(void* const* d_in, const int* in_sizes, int n_in,
                              void* d_out, int out_size, void* d_ws, size_t ws_size,
                              hipStream_t stream) {
    const float* x   = (const float*)d_in[0];
    const int*   ei  = (const int*)d_in[1];
    const float* ea  = (const float*)d_in[2];
    const float* W1l = (const float*)d_in[3];
    const float* b1l = (const float*)d_in[4];
    const float* W1r = (const float*)d_in[5];
    const float* W2l = (const float*)d_in[6];
    const float* b2l = (const float*)d_in[7];
    const float* W2r = (const float*)d_in[8];
    float* out = (float*)d_out;

    const int N = in_sizes[0] / D;   // 50000
    const int E = in_sizes[1] / 2;   // 1,600,000
    const int* src = ei;
    const int* dst = ei + E;

    char* ws = (char*)d_ws;
    size_t o = 0;
    auto alloc = [&](size_t bytes) -> void* {
        void* p = ws + o;
        o = (o + bytes + 255) & ~(size_t)255;
        return p;
    };
    int*   cnt    = (int*)alloc((size_t)N * 4);
    int*   off    = (int*)alloc((size_t)(N + 1) * 4);
    int*   cursor = (int*)alloc((size_t)N * 4);
    int2*  pairs  = (int2*)alloc((size_t)E * 8);
    float* agg    = (float*)alloc((size_t)N * D * 4);
    float* z1     = (float*)alloc((size_t)N * D * 4);
    (void)ws_size; (void)n_in; (void)out_size;

    // Build dst-sorted CSR (reused by both layers)
    hipMemsetAsync(cnt, 0, (size_t)N * 4, stream);
    count_kernel<<<(E + 255) / 256, 256, 0, stream>>>(dst, cnt, E);
    scan_kernel<<<1, 1024, 0, stream>>>(cnt, off, cursor, N);
    fill_kernel<<<(E + 255) / 256, 256, 0, stream>>>(src, dst, cursor, pairs, E);

    // Layer 1
    aggregate_kernel<<<N, 64, 0, stream>>>(x, ea, off, pairs, agg);
    gemm_fused_kernel<1><<<(N + 63) / 64, 256, 0, stream>>>(agg, x, W1l, W1r, b1l, z1, N);
    // Layer 2
    aggregate_kernel<<<N, 64, 0, stream>>>(z1, ea, off, pairs, agg);
    gemm_fused_kernel<0><<<(N + 63) / 64, 256, 0, stream>>>(agg, z1, W2l, W2r, b2l, out, N);
}

// Round 2
// 651.701 us; speedup vs baseline: 1.3334x; 1.3334x over previous
//
#include <hip/hip_runtime.h>

#define D 128

typedef __attribute__((ext_vector_type(8))) short bf16x8;   // 8 bf16 (4 VGPRs)
typedef __attribute__((ext_vector_type(4))) float f32x4;    // MFMA accum

__device__ inline unsigned short f2bf(float f) {
    union { float f; unsigned u; } v; v.f = f;
    unsigned r = v.u + 0x7FFF + ((v.u >> 16) & 1);   // RNE
    return (unsigned short)(r >> 16);
}
__device__ inline float bf2f(unsigned short h) {
    union { unsigned u; float f; } v; v.u = ((unsigned)h) << 16; return v.f;
}

// ---------------- casts ----------------

__global__ __launch_bounds__(256) void castx_kernel(const float* __restrict__ x,
                                                    unsigned short* __restrict__ xb, int n4) {
    int i = blockIdx.x * 256 + threadIdx.x;
    if (i < n4) {
        float4 v = reinterpret_cast<const float4*>(x)[i];
        ushort4 r;
        r.x = f2bf(v.x); r.y = f2bf(v.y); r.z = f2bf(v.z); r.w = f2bf(v.w);
        reinterpret_cast<ushort4*>(xb)[i] = r;
    }
}

// Wt[c][k] bf16, k in [0,256): k<128 -> Wl[k][c], k>=128 -> Wr[k-128][c]
__global__ __launch_bounds__(256) void wcast_kernel(const float* __restrict__ W1l,
                                                    const float* __restrict__ W1r,
                                                    const float* __restrict__ W2l,
                                                    const float* __restrict__ W2r,
                                                    unsigned short* __restrict__ Wt1,
                                                    unsigned short* __restrict__ Wt2) {
    int c = blockIdx.x, k = threadIdx.x;
    float v1 = (k < 128) ? W1l[k * 128 + c] : W1r[(k - 128) * 128 + c];
    float v2 = (k < 128) ? W2l[k * 128 + c] : W2r[(k - 128) * 128 + c];
    Wt1[c * 256 + k] = f2bf(v1);
    Wt2[c * 256 + k] = f2bf(v2);
}

// ---------------- CSR build ----------------

__global__ __launch_bounds__(256) void count_kernel(const int* __restrict__ dst,
                                                    int* __restrict__ cnt, int E) {
    int e = blockIdx.x * 256 + threadIdx.x;
    if (e < E) atomicAdd(&cnt[dst[e]], 1);
}

// hierarchical scan: 1024 elems per block
__global__ __launch_bounds__(256) void psum_kernel(const int* __restrict__ cnt,
                                                   int* __restrict__ bsum, int n) {
    __shared__ int wsh[4];
    int b = blockIdx.x, tid = threadIdx.x;
    int i0 = b * 1024 + tid * 4;
    int s = 0;
    #pragma unroll
    for (int j = 0; j < 4; ++j) { int i = i0 + j; if (i < n) s += cnt[i]; }
    #pragma unroll
    for (int d = 1; d < 64; d <<= 1) s += __shfl_xor(s, d, 64);
    if ((tid & 63) == 0) wsh[tid >> 6] = s;
    __syncthreads();
    if (tid == 0) bsum[b] = wsh[0] + wsh[1] + wsh[2] + wsh[3];
}

__global__ __launch_bounds__(64) void bscan_kernel(const int* __restrict__ bsum,
                                                   int* __restrict__ bpre, int nb) {
    int t = threadIdx.x;
    int v = (t < nb) ? bsum[t] : 0;
    int sc = v;
    #pragma unroll
    for (int d = 1; d < 64; d <<= 1) { int u = __shfl_up(sc, d, 64); if (t >= d) sc += u; }
    if (t < nb) bpre[t] = sc - v;
}

__global__ __launch_bounds__(256) void fscan_kernel(const int* __restrict__ cnt,
                                                    const int* __restrict__ bpre,
                                                    int* __restrict__ off,
                                                    int* __restrict__ cursor, int n) {
    __shared__ int wsum[4];
    int b = blockIdx.x, tid = threadIdx.x;
    int lane = tid & 63, wv = tid >> 6;
    int i0 = b * 1024 + tid * 4;
    int v[4]; int s = 0;
    #pragma unroll
    for (int j = 0; j < 4; ++j) { int i = i0 + j; v[j] = (i < n) ? cnt[i] : 0; s += v[j]; }
    int sc = s;
    #pragma unroll
    for (int d = 1; d < 64; d <<= 1) { int u = __shfl_up(sc, d, 64); if (lane >= d) sc += u; }
    if (lane == 63) wsum[wv] = sc;
    __syncthreads();
    int wp = 0;
    for (int j = 0; j < wv; ++j) wp += wsum[j];
    int base = bpre[b] + wp + sc - s;   // exclusive prefix of first elem
    #pragma unroll
    for (int j = 0; j < 4; ++j) {
        int i = i0 + j;
        if (i < n) { cursor[i] = base; off[i + 1] = base + v[j]; }
        base += v[j];
    }
    if (b == 0 && tid == 0) off[0] = 0;
}

__global__ __launch_bounds__(256) void fill_kernel(const int* __restrict__ src,
                                                   const int* __restrict__ dst,
                                                   int* __restrict__ cursor,
                                                   int2* __restrict__ pairs, int E) {
    int e = blockIdx.x * 256 + threadIdx.x;
    if (e < E) {
        int d = dst[e];
        int slot = atomicAdd(&cursor[d], 1);
        pairs[slot] = make_int2(src[e], e);
    }
}

// ---------------- mean aggregation: agg = mean_dst relu(feat[src] + ea) ----------------
// 1 wave per node; two half-waves process alternating edges; float4 per 32-lane half.

__global__ __launch_bounds__(64) void aggregate_kernel(const unsigned short* __restrict__ featb,
                                                       const float* __restrict__ ea,
                                                       const int* __restrict__ off,
                                                       const int2* __restrict__ pairs,
                                                       unsigned short* __restrict__ aggb) {
    int nd = blockIdx.x;
    int t = threadIdx.x;
    int half = t >> 5, l32 = t & 31;
    int s = off[nd], e = off[nd + 1];
    float a0 = 0.f, a1 = 0.f, a2 = 0.f, a3 = 0.f;
    for (int p = s + half; p < e; p += 2) {
        int2 pr = pairs[p];
        const float4 ev = *reinterpret_cast<const float4*>(&ea[(size_t)pr.y * D + l32 * 4]);
        const ushort4 xv = *reinterpret_cast<const ushort4*>(&featb[(size_t)pr.x * D + l32 * 4]);
        a0 += fmaxf(bf2f(xv.x) + ev.x, 0.f);
        a1 += fmaxf(bf2f(xv.y) + ev.y, 0.f);
        a2 += fmaxf(bf2f(xv.z) + ev.z, 0.f);
        a3 += fmaxf(bf2f(xv.w) + ev.w, 0.f);
    }
    a0 += __shfl_xor(a0, 32, 64);
    a1 += __shfl_xor(a1, 32, 64);
    a2 += __shfl_xor(a2, 32, 64);
    a3 += __shfl_xor(a3, 32, 64);
    int deg = e - s;
    float inv = 1.f / (float)(deg > 0 ? deg : 1);
    if (t < 32) {
        ushort4 r;
        r.x = f2bf(a0 * inv); r.y = f2bf(a1 * inv);
        r.z = f2bf(a2 * inv); r.w = f2bf(a3 * inv);
        *reinterpret_cast<ushort4*>(&aggb[(size_t)nd * D + l32 * 4]) = r;
    }
}

// ---------------- MFMA GEMM: out = act([A1|A2](Nx256) @ Wt^T + bias) ----------------
// 4 waves/block; wave w owns cols [32w, 32w+32) as 2 16-col tiles; B-frags persist
// in registers (2 tiles x 8 k-chunks). Grid-stride over 16-row M-tiles. No LDS.
// mfma_f32_16x16x32_bf16 layout: A lane: row=l&15, k=(l>>4)*8+j (contiguous);
// B lane: col=l&15, k=(l>>4)*8+j; D lane: row=(l>>4)*4+r, col=l&15 (m89-verified).

template <int RELU, int OUT_BF16>
__global__ __launch_bounds__(256) void gemm_mfma_kernel(const unsigned short* __restrict__ A1,
                                                        const unsigned short* __restrict__ A2,
                                                        const unsigned short* __restrict__ Wt,
                                                        const float* __restrict__ bias,
                                                        float* __restrict__ outf,
                                                        unsigned short* __restrict__ outb,
                                                        int MT) {
    int tid = threadIdx.x;
    int w = tid >> 6;
    int l = tid & 63;
    int lr = l & 15;
    int lg = l >> 4;
    int c0 = w * 32;

    bf16x8 bfr[2][8];
    #pragma unroll
    for (int t = 0; t < 2; ++t)
        #pragma unroll
        for (int kc = 0; kc < 8; ++kc)
            bfr[t][kc] = *reinterpret_cast<const bf16x8*>(
                &Wt[(size_t)(c0 + t * 16 + lr) * 256 + kc * 32 + lg * 8]);

    for (int mt = blockIdx.x; mt < MT; mt += gridDim.x) {
        int r0 = mt * 16;
        f32x4 acc0 = {0.f, 0.f, 0.f, 0.f};
        f32x4 acc1 = {0.f, 0.f, 0.f, 0.f};
        #pragma unroll
        for (int kc = 0; kc < 8; ++kc) {
            const unsigned short* Ap = (kc < 4) ? A1 : A2;
            int k = (kc & 3) * 32 + lg * 8;
            bf16x8 af = *reinterpret_cast<const bf16x8*>(&Ap[(size_t)(r0 + lr) * D + k]);
            acc0 = __builtin_amdgcn_mfma_f32_16x16x32_bf16(af, bfr[0][kc], acc0, 0, 0, 0);
            acc1 = __builtin_amdgcn_mfma_f32_16x16x32_bf16(af, bfr[1][kc], acc1, 0, 0, 0);
        }
        #pragma unroll
        for (int t = 0; t < 2; ++t) {
            const f32x4& a = t ? acc1 : acc0;
            int col = c0 + t * 16 + lr;
            float bv = bias[col];
            #pragma unroll
            for (int r = 0; r < 4; ++r) {
                int row = r0 + lg * 4 + r;
                float v = a[r] + bv;
                if (RELU) v = fmaxf(v, 0.f);
                if (OUT_BF16) outb[(size_t)row * D + col] = f2bf(v);
                else outf[(size_t)row * D + col] = v;
            }
        }
    }
}

extern "C" void kernel_launch(void* const* d_in, const int* in_sizes, int n_in,
                              void* d_out, int out_size, void* d_ws, size_t ws_size,
                              hipStream_t stream) {
    const float* x   = (const float*)d_in[0];
    const int*   ei  = (const int*)d_in[1];
    const float* ea  = (const float*)d_in[2];
    const float* W1l = (const float*)d_in[3];
    const float* b1l = (const float*)d_in[4];
    const float* W1r = (const float*)d_in[5];
    const float* W2l = (const float*)d_in[6];
    const float* b2l = (const float*)d_in[7];
    const float* W2r = (const float*)d_in[8];
    float* out = (float*)d_out;

    const int N = in_sizes[0] / D;   // 50000
    const int E = in_sizes[1] / 2;   // 1,600,000
    const int* src = ei;
    const int* dst = ei + E;

    char* ws = (char*)d_ws;
    size_t o = 0;
    auto alloc = [&](size_t bytes) -> void* {
        void* p = ws + o;
        o = (o + bytes + 255) & ~(size_t)255;
        return p;
    };
    int*   cnt    = (int*)alloc((size_t)N * 4);
    int*   off    = (int*)alloc((size_t)(N + 1) * 4);
    int*   cursor = (int*)alloc((size_t)N * 4);
    int*   bsum   = (int*)alloc(256 * 4);
    int*   bpre   = (int*)alloc(256 * 4);
    int2*  pairs  = (int2*)alloc((size_t)E * 8);
    unsigned short* xb   = (unsigned short*)alloc((size_t)N * D * 2);
    unsigned short* z1b  = (unsigned short*)alloc((size_t)N * D * 2);
    unsigned short* aggb = (unsigned short*)alloc((size_t)N * D * 2);
    unsigned short* Wt1  = (unsigned short*)alloc(128 * 256 * 2);
    unsigned short* Wt2  = (unsigned short*)alloc(128 * 256 * 2);
    (void)ws_size; (void)n_in; (void)out_size;

    const int MT = N / 16;           // 3125 (N % 16 == 0)
    const int NB = (N + 1023) / 1024;  // 49 scan blocks (<= 64)

    // casts (independent of CSR build)
    castx_kernel<<<(N * D / 4 + 255) / 256, 256, 0, stream>>>(x, xb, N * D / 4);
    wcast_kernel<<<128, 256, 0, stream>>>(W1l, W1r, W2l, W2r, Wt1, Wt2);

    // CSR build
    hipMemsetAsync(cnt, 0, (size_t)N * 4, stream);
    count_kernel<<<(E + 255) / 256, 256, 0, stream>>>(dst, cnt, E);
    psum_kernel<<<NB, 256, 0, stream>>>(cnt, bsum, N);
    bscan_kernel<<<1, 64, 0, stream>>>(bsum, bpre, NB);
    fscan_kernel<<<NB, 256, 0, stream>>>(cnt, bpre, off, cursor, N);
    fill_kernel<<<(E + 255) / 256, 256, 0, stream>>>(src, dst, cursor, pairs, E);

    // Layer 1: agg = mean relu(x[src]+ea); z1 = relu(agg@W1l + b1l + x@W1r)  (bf16)
    aggregate_kernel<<<N, 64, 0, stream>>>(xb, ea, off, pairs, aggb);
    gemm_mfma_kernel<1, 1><<<1024, 256, 0, stream>>>(aggb, xb, Wt1, b1l, nullptr, z1b, MT);

    // Layer 2: agg = mean relu(z1[src]+ea); out = agg@W2l + b2l + z1@W2r  (f32 out)
    aggregate_kernel<<<N, 64, 0, stream>>>(z1b, ea, off, pairs, aggb);
    gemm_mfma_kernel<0, 0><<<1024, 256, 0, stream>>>(aggb, z1b, Wt2, b2l, out, nullptr, MT);
}

// Round 6
// 603.706 us; speedup vs baseline: 1.4394x; 1.0795x over previous
//
#include <hip/hip_runtime.h>

#define D 128

typedef __attribute__((ext_vector_type(8))) short bf16x8;   // 8 bf16 (4 VGPRs)
typedef __attribute__((ext_vector_type(4))) float f32x4;    // MFMA accum

__device__ inline unsigned short f2bf(float f) {
    union { float f; unsigned u; } v; v.f = f;
    unsigned r = v.u + 0x7FFF + ((v.u >> 16) & 1);   // RNE
    return (unsigned short)(r >> 16);
}
__device__ inline float bf2f(unsigned short h) {
    union { unsigned u; float f; } v; v.u = ((unsigned)h) << 16; return v.f;
}

// ---------------- casts ----------------

__global__ __launch_bounds__(256) void castx_kernel(const float* __restrict__ x,
                                                    unsigned short* __restrict__ xb, int n4) {
    int i = blockIdx.x * 256 + threadIdx.x;
    if (i < n4) {
        float4 v = reinterpret_cast<const float4*>(x)[i];
        ushort4 r;
        r.x = f2bf(v.x); r.y = f2bf(v.y); r.z = f2bf(v.z); r.w = f2bf(v.w);
        reinterpret_cast<ushort4*>(xb)[i] = r;
    }
}

// Wt[c][k] bf16, k in [0,256): k<128 -> Wl[k][c], k>=128 -> Wr[k-128][c]
__global__ __launch_bounds__(256) void wcast_kernel(const float* __restrict__ W1l,
                                                    const float* __restrict__ W1r,
                                                    const float* __restrict__ W2l,
                                                    const float* __restrict__ W2r,
                                                    unsigned short* __restrict__ Wt1,
                                                    unsigned short* __restrict__ Wt2) {
    int c = blockIdx.x, k = threadIdx.x;
    float v1 = (k < 128) ? W1l[k * 128 + c] : W1r[(k - 128) * 128 + c];
    float v2 = (k < 128) ? W2l[k * 128 + c] : W2r[(k - 128) * 128 + c];
    Wt1[c * 256 + k] = f2bf(v1);
    Wt2[c * 256 + k] = f2bf(v2);
}

// ---------------- CSR build ----------------

__global__ __launch_bounds__(256) void count_kernel(const int* __restrict__ dst,
                                                    int* __restrict__ cnt, int E) {
    int e = blockIdx.x * 256 + threadIdx.x;
    if (e < E) atomicAdd(&cnt[dst[e]], 1);
}

// hierarchical scan: 1024 elems per block
__global__ __launch_bounds__(256) void psum_kernel(const int* __restrict__ cnt,
                                                   int* __restrict__ bsum, int n) {
    __shared__ int wsh[4];
    int b = blockIdx.x, tid = threadIdx.x;
    int i0 = b * 1024 + tid * 4;
    int s = 0;
    #pragma unroll
    for (int j = 0; j < 4; ++j) { int i = i0 + j; if (i < n) s += cnt[i]; }
    #pragma unroll
    for (int d = 1; d < 64; d <<= 1) s += __shfl_xor(s, d, 64);
    if ((tid & 63) == 0) wsh[tid >> 6] = s;
    __syncthreads();
    if (tid == 0) bsum[b] = wsh[0] + wsh[1] + wsh[2] + wsh[3];
}

__global__ __launch_bounds__(64) void bscan_kernel(const int* __restrict__ bsum,
                                                   int* __restrict__ bpre, int nb) {
    int t = threadIdx.x;
    int v = (t < nb) ? bsum[t] : 0;
    int sc = v;
    #pragma unroll
    for (int d = 1; d < 64; d <<= 1) { int u = __shfl_up(sc, d, 64); if (t >= d) sc += u; }
    if (t < nb) bpre[t] = sc - v;
}

__global__ __launch_bounds__(256) void fscan_kernel(const int* __restrict__ cnt,
                                                    const int* __restrict__ bpre,
                                                    int* __restrict__ off,
                                                    int* __restrict__ cursor, int n) {
    __shared__ int wsum[4];
    int b = blockIdx.x, tid = threadIdx.x;
    int lane = tid & 63, wv = tid >> 6;
    int i0 = b * 1024 + tid * 4;
    int v[4]; int s = 0;
    #pragma unroll
    for (int j = 0; j < 4; ++j) { int i = i0 + j; v[j] = (i < n) ? cnt[i] : 0; s += v[j]; }
    int sc = s;
    #pragma unroll
    for (int d = 1; d < 64; d <<= 1) { int u = __shfl_up(sc, d, 64); if (lane >= d) sc += u; }
    if (lane == 63) wsum[wv] = sc;
    __syncthreads();
    int wp = 0;
    for (int j = 0; j < wv; ++j) wp += wsum[j];
    int base = bpre[b] + wp + sc - s;   // exclusive prefix of first elem
    #pragma unroll
    for (int j = 0; j < 4; ++j) {
        int i = i0 + j;
        if (i < n) { cursor[i] = base; off[i + 1] = base + v[j]; }
        base += v[j];
    }
    if (b == 0 && tid == 0) off[0] = 0;
}

__global__ __launch_bounds__(256) void fill_kernel(const int* __restrict__ src,
                                                   const int* __restrict__ dst,
                                                   int* __restrict__ cursor,
                                                   int2* __restrict__ pairs, int E) {
    int e = blockIdx.x * 256 + threadIdx.x;
    if (e < E) {
        int d = dst[e];
        int slot = atomicAdd(&cursor[d], 1);
        pairs[slot] = make_int2(src[e], e);
    }
}

// ---------------- mean aggregation: agg = mean_dst relu(feat[src] + ea) ----------------
// 4 waves/block, 1 node/wave, half-wave per edge. Wave batch-preloads 64 CSR pairs,
// broadcasts via shfl. ALL shfl calls are exec-uniform: branch conditions around
// process() are wave-uniform; the final odd edge is handled with all 64 lanes
// active and accumulation guarded to half 0 (guard contains no shfl).

__global__ __launch_bounds__(256) void aggregate_kernel(const unsigned short* __restrict__ featb,
                                                        const float* __restrict__ ea,
                                                        const int* __restrict__ off,
                                                        const long long* __restrict__ pairs,
                                                        unsigned short* __restrict__ aggb,
                                                        int N) {
    int nd = blockIdx.x * 4 + (threadIdx.x >> 6);
    if (nd >= N) return;
    int t = threadIdx.x & 63;
    int half = t >> 5, l32 = t & 31;
    int s = off[nd], e = off[nd + 1];
    float a0 = 0.f, a1 = 0.f, a2 = 0.f, a3 = 0.f;

    for (int b = s; b < e; b += 64) {
        int cnt = min(64, e - b);
        long long prl = (b + t < e) ? __builtin_nontemporal_load(&pairs[b + t]) : 0LL;
        int psrc = (int)(prl & 0xFFFFFFFFLL);            // pairs[].x = src
        int peid = (int)((unsigned long long)prl >> 32); // pairs[].y = edge id

        auto fetch = [&](int idx, float4& ev, ushort4& xv) {
            int sidx = __shfl(psrc, idx, 64);
            int eidx = __shfl(peid, idx, 64);
            const float* ep = &ea[(size_t)eidx * D + l32 * 4];
            ev = make_float4(__builtin_nontemporal_load(ep + 0),
                             __builtin_nontemporal_load(ep + 1),
                             __builtin_nontemporal_load(ep + 2),
                             __builtin_nontemporal_load(ep + 3));
            xv = *reinterpret_cast<const ushort4*>(&featb[(size_t)sidx * D + l32 * 4]);
        };
        auto accum = [&](const float4& ev, const ushort4& xv) {
            a0 += fmaxf(bf2f(xv.x) + ev.x, 0.f);
            a1 += fmaxf(bf2f(xv.y) + ev.y, 0.f);
            a2 += fmaxf(bf2f(xv.z) + ev.z, 0.f);
            a3 += fmaxf(bf2f(xv.w) + ev.w, 0.f);
        };

        int p = 0;
        for (; p + 4 <= cnt; p += 4) {          // uniform condition
            float4 e0; ushort4 x0; fetch(p + half, e0, x0);
            float4 e1; ushort4 x1; fetch(p + 2 + half, e1, x1);
            accum(e0, x0);
            accum(e1, x1);
        }
        if (p + 2 <= cnt) {                     // uniform condition
            float4 e0; ushort4 x0; fetch(p + half, e0, x0);
            accum(e0, x0);
            p += 2;
        }
        if (p < cnt) {                          // uniform condition; 1 edge left
            float4 e0; ushort4 x0; fetch(p, e0, x0);  // all 64 lanes shfl/load
            if (half == 0) accum(e0, x0);       // no shfl inside guard
        }
    }

    a0 += __shfl_xor(a0, 32, 64);
    a1 += __shfl_xor(a1, 32, 64);
    a2 += __shfl_xor(a2, 32, 64);
    a3 += __shfl_xor(a3, 32, 64);
    int deg = e - s;
    float inv = 1.f / (float)(deg > 0 ? deg : 1);
    if (half == 0) {
        ushort4 r;
        r.x = f2bf(a0 * inv); r.y = f2bf(a1 * inv);
        r.z = f2bf(a2 * inv); r.w = f2bf(a3 * inv);
        *reinterpret_cast<ushort4*>(&aggb[(size_t)nd * D + l32 * 4]) = r;
    }
}

// ---------------- MFMA GEMM: out = act([A1|A2](Nx256) @ Wt^T + bias) ----------------
// 4 waves/block; wave w owns cols [32w, 32w+32) as 2 16-col tiles; B-frags persist
// in registers (2 tiles x 8 k-chunks). Grid-stride over 16-row M-tiles. No LDS.

template <int RELU, int OUT_BF16>
__global__ __launch_bounds__(256) void gemm_mfma_kernel(const unsigned short* __restrict__ A1,
                                                        const unsigned short* __restrict__ A2,
                                                        const unsigned short* __restrict__ Wt,
                                                        const float* __restrict__ bias,
                                                        float* __restrict__ outf,
                                                        unsigned short* __restrict__ outb,
                                                        int MT) {
    int tid = threadIdx.x;
    int w = tid >> 6;
    int l = tid & 63;
    int lr = l & 15;
    int lg = l >> 4;
    int c0 = w * 32;

    bf16x8 bfr[2][8];
    #pragma unroll
    for (int t = 0; t < 2; ++t)
        #pragma unroll
        for (int kc = 0; kc < 8; ++kc)
            bfr[t][kc] = *reinterpret_cast<const bf16x8*>(
                &Wt[(size_t)(c0 + t * 16 + lr) * 256 + kc * 32 + lg * 8]);

    for (int mt = blockIdx.x; mt < MT; mt += gridDim.x) {
        int r0 = mt * 16;
        f32x4 acc0 = {0.f, 0.f, 0.f, 0.f};
        f32x4 acc1 = {0.f, 0.f, 0.f, 0.f};
        #pragma unroll
        for (int kc = 0; kc < 8; ++kc) {
            const unsigned short* Ap = (kc < 4) ? A1 : A2;
            int k = (kc & 3) * 32 + lg * 8;
            bf16x8 af = *reinterpret_cast<const bf16x8*>(&Ap[(size_t)(r0 + lr) * D + k]);
            acc0 = __builtin_amdgcn_mfma_f32_16x16x32_bf16(af, bfr[0][kc], acc0, 0, 0, 0);
            acc1 = __builtin_amdgcn_mfma_f32_16x16x32_bf16(af, bfr[1][kc], acc1, 0, 0, 0);
        }
        #pragma unroll
        for (int t = 0; t < 2; ++t) {
            const f32x4& a = t ? acc1 : acc0;
            int col = c0 + t * 16 + lr;
            float bv = bias[col];
            #pragma unroll
            for (int r = 0; r < 4; ++r) {
                int row = r0 + lg * 4 + r;
                float v = a[r] + bv;
                if (RELU) v = fmaxf(v, 0.f);
                if (OUT_BF16) outb[(size_t)row * D + col] = f2bf(v);
                else outf[(size_t)row * D + col] = v;
            }
        }
    }
}

extern "C" void kernel_launch(void* const* d_in, const int* in_sizes, int n_in,
                              void* d_out, int out_size, void* d_ws, size_t ws_size,
                              hipStream_t stream) {
    const float* x   = (const float*)d_in[0];
    const int*   ei  = (const int*)d_in[1];
    const float* ea  = (const float*)d_in[2];
    const float* W1l = (const float*)d_in[3];
    const float* b1l = (const float*)d_in[4];
    const float* W1r = (const float*)d_in[5];
    const float* W2l = (const float*)d_in[6];
    const float* b2l = (const float*)d_in[7];
    const float* W2r = (const float*)d_in[8];
    float* out = (float*)d_out;

    const int N = in_sizes[0] / D;   // 50000
    const int E = in_sizes[1] / 2;   // 1,600,000
    const int* src = ei;
    const int* dst = ei + E;

    char* ws = (char*)d_ws;
    size_t o = 0;
    auto alloc = [&](size_t bytes) -> void* {
        void* p = ws + o;
        o = (o + bytes + 255) & ~(size_t)255;
        return p;
    };
    int*   cnt    = (int*)alloc((size_t)N * 4);
    int*   off    = (int*)alloc((size_t)(N + 1) * 4);
    int*   cursor = (int*)alloc((size_t)N * 4);
    int*   bsum   = (int*)alloc(256 * 4);
    int*   bpre   = (int*)alloc(256 * 4);
    int2*  pairs  = (int2*)alloc((size_t)E * 8);
    unsigned short* xb   = (unsigned short*)alloc((size_t)N * D * 2);
    unsigned short* z1b  = (unsigned short*)alloc((size_t)N * D * 2);
    unsigned short* aggb = (unsigned short*)alloc((size_t)N * D * 2);
    unsigned short* Wt1  = (unsigned short*)alloc(128 * 256 * 2);
    unsigned short* Wt2  = (unsigned short*)alloc(128 * 256 * 2);
    (void)ws_size; (void)n_in; (void)out_size;

    const int MT = N / 16;             // 3125 (N % 16 == 0)
    const int NB = (N + 1023) / 1024;  // 49 scan blocks (<= 64)
    const int AGB = (N + 3) / 4;       // aggregate blocks (4 nodes each)

    // casts (independent of CSR build)
    castx_kernel<<<(N * D / 4 + 255) / 256, 256, 0, stream>>>(x, xb, N * D / 4);
    wcast_kernel<<<128, 256, 0, stream>>>(W1l, W1r, W2l, W2r, Wt1, Wt2);

    // CSR build
    (void)hipMemsetAsync(cnt, 0, (size_t)N * 4, stream);
    count_kernel<<<(E + 255) / 256, 256, 0, stream>>>(dst, cnt, E);
    psum_kernel<<<NB, 256, 0, stream>>>(cnt, bsum, N);
    bscan_kernel<<<1, 64, 0, stream>>>(bsum, bpre, NB);
    fscan_kernel<<<NB, 256, 0, stream>>>(cnt, bpre, off, cursor, N);
    fill_kernel<<<(E + 255) / 256, 256, 0, stream>>>(src, dst, cursor, pairs, E);

    // Layer 1: agg = mean relu(x[src]+ea); z1 = relu(agg@W1l + b1l + x@W1r)  (bf16)
    aggregate_kernel<<<AGB, 256, 0, stream>>>(xb, ea, off, (const long long*)pairs, aggb, N);
    gemm_mfma_kernel<1, 1><<<1024, 256, 0, stream>>>(aggb, xb, Wt1, b1l, nullptr, z1b, MT);

    // Layer 2: agg = mean relu(z1[src]+ea); out = agg@W2l + b2l + z1@W2r  (f32 out)
    aggregate_kernel<<<AGB, 256, 0, stream>>>(z1b, ea, off, (const long long*)pairs, aggb, N);
    gemm_mfma_kernel<0, 0><<<1024, 256, 0, stream>>>(aggb, z1b, Wt2, b2l, out, nullptr, MT);
}